// Round 2
// baseline (8500.788 us; speedup 1.0000x reference)
//
#include <hip/hip_runtime.h>

// ---------------------------------------------------------------------------
// Sizes (fixed by the problem)
// ---------------------------------------------------------------------------
constexpr int S_ = 256, U_ = 64, H_ = 512, H2_ = 256, V_ = 5000;
constexpr int K1_ = H_ + H2_;       // 768  (x_emb | t_emb1)
constexpr int K2_ = 2 * H_ + H2_;   // 1280 (out_w | p_u | t_emb2)

#define PI_F 3.14159265358979323846f

// ---------------------------------------------------------------------------
// Workspace layout (float offsets). Total = 21,699,072 floats = 86.8 MB.
// ---------------------------------------------------------------------------
constexpr size_t WW_OFF    = 0;          // 168*168  = 28224 (padded to 28672)
constexpr size_t TAB_OFF   = 28672;      // 168*256  = 43008
constexpr size_t WC_OFF    = 71680;      // 512*768  = 393216  (W_ih @ fcpt_w)
constexpr size_t BIASC_OFF = 464896;     // 512
constexpr size_t WHHT_OFF  = 465408;     // 512*512  = 262144  (W_hh transposed)
constexpr size_t XIH_OFF   = 727552;     // 16384*512 = 8388608 (reused as OUTW)
constexpr size_t RNN_OFF   = 9116160;    // 64*256*512 = 8388608 ([u][s][h])
constexpr size_t WN_OFF    = 17504768;   // 64*256*256 = 4194304 (normalized attn W)
constexpr size_t OUTW_OFF  = XIH_OFF;    // Xih dead after RNN -> reuse

// ---------------------------------------------------------------------------
// K1: week_weight[i][j] = gauss(sigma_i, wwi[i][j]) row-normalized
// ---------------------------------------------------------------------------
__global__ void k_week(const float* __restrict__ sigma,
                       const float* __restrict__ wwi,
                       float* __restrict__ ww)
{
    const int i = blockIdx.x;
    const int j = threadIdx.x;                 // 256 threads, 168 active
    const float sig  = fabsf(sigma[i]);
    const float sig2 = sig * sig;
    float v = 0.f;
    if (j < 168) {
        const float xv = wwi[i * 168 + j];
        v = (1.f / sqrtf(2.f * PI_F * sig2)) * expf(-(xv * xv) / (2.f * sig2));
    }
    __shared__ float red[256];
    red[j] = v;
    __syncthreads();
    for (int st = 128; st > 0; st >>= 1) {
        if (j < st) red[j] += red[j + st];
        __syncthreads();
    }
    const float den = red[0];
    if (j < 168) ww[i * 168 + j] = v / den;
}

// ---------------------------------------------------------------------------
// K2: tab[slot][h] = sum_k ww[slot][k] * wenc[wm[slot][k]][h]   (h < 256)
// ---------------------------------------------------------------------------
__global__ void k_table(const float* __restrict__ ww,
                        const int* __restrict__ wm,
                        const float* __restrict__ wenc,
                        float* __restrict__ tab)
{
    const int slot = blockIdx.x;
    const int t = threadIdx.x;                 // 256 = H2
    __shared__ float wws[168];
    __shared__ int   wms[168];
    if (t < 168) {
        wws[t] = ww[slot * 168 + t];
        wms[t] = wm[slot * 168 + t];
    }
    __syncthreads();
    float acc = 0.f;
    #pragma unroll 4
    for (int k = 0; k < 168; ++k)
        acc = fmaf(wws[k], wenc[(size_t)wms[k] * H2_ + t], acc);
    tab[(size_t)slot * H2_ + t] = acc;
}

// ---------------------------------------------------------------------------
// K3: Wc[n][k] = sum_m W_ih[n][m] * fcpt_w[m][k]   (512 x 768, K=512)
// ---------------------------------------------------------------------------
__global__ void k_wc(const float* __restrict__ W_ih,
                     const float* __restrict__ fcpt_w,
                     float* __restrict__ Wc)
{
    const int kk = blockIdx.x * 256 + threadIdx.x;   // 0..767
    const int n0 = blockIdx.y * 16;
    float acc[16] = {};
    for (int m = 0; m < H_; ++m) {
        const float fw = fcpt_w[(size_t)m * K1_ + kk];
        #pragma unroll
        for (int j = 0; j < 16; ++j)
            acc[j] = fmaf(W_ih[(size_t)(n0 + j) * H_ + m], fw, acc[j]);
    }
    #pragma unroll
    for (int j = 0; j < 16; ++j)
        Wc[(size_t)(n0 + j) * K1_ + kk] = acc[j];
}

// K3b: biasc[n] = b_ih[n] + b_hh[n] + sum_k W_ih[n][k] * fcpt_b[k]
__global__ void k_biasc(const float* __restrict__ W_ih,
                        const float* __restrict__ fcpt_b,
                        const float* __restrict__ b_ih,
                        const float* __restrict__ b_hh,
                        float* __restrict__ biasc)
{
    const int n = blockIdx.x * 256 + threadIdx.x;
    float acc = b_ih[n] + b_hh[n];
    for (int k = 0; k < H_; ++k)
        acc = fmaf(W_ih[(size_t)n * H_ + k], fcpt_b[k], acc);
    biasc[n] = acc;
}

// ---------------------------------------------------------------------------
// K4: WhhT[k][o] = W_hh[o][k]  (512x512 transpose, 32x32 LDS tiles)
// ---------------------------------------------------------------------------
__global__ void k_whhT(const float* __restrict__ Whh, float* __restrict__ WhhT)
{
    __shared__ float tile[32][33];
    const int bx = blockIdx.x, by = blockIdx.y;
    const int tx = threadIdx.x;                // 0..31
    for (int r = threadIdx.y; r < 32; r += 8)
        tile[r][tx] = Whh[(size_t)(by * 32 + r) * H_ + bx * 32 + tx];
    __syncthreads();
    for (int r = threadIdx.y; r < 32; r += 8)
        WhhT[(size_t)(bx * 32 + r) * H_ + by * 32 + tx] = tile[tx][r];
}

// ---------------------------------------------------------------------------
// K5: gathered GEMM  Xih[m][n] = sum_k A1[m][k] * Wc[n][k] + biasc[n]
// ---------------------------------------------------------------------------
__global__ __launch_bounds__(256) void k_xih_gemm(
    const int* __restrict__ x, const int* __restrict__ tslot,
    const float* __restrict__ enc_w, const float* __restrict__ tab,
    const float* __restrict__ Wc, const float* __restrict__ biasc,
    float* __restrict__ Xih)
{
    __shared__ float As[16][132];
    __shared__ float Bs[16][132];
    const int t = threadIdx.x;
    const int n0 = blockIdx.x * 128;
    const int m0 = blockIdx.y * 128;
    const int lrow = t >> 2;
    const int lk = (t & 3) << 2;
    const int tx = t & 15, ty = t >> 4;
    float acc[8][8] = {};
    for (int k0 = 0; k0 < K1_; k0 += 16) {
        const int kg = k0 + lk;
        #pragma unroll
        for (int hh = 0; hh < 2; ++hh) {
            const int m = m0 + lrow + hh * 64;
            const float* ap;
            if (kg < 512) ap = enc_w + (size_t)x[m] * H_ + kg;
            else          ap = tab + (size_t)tslot[m] * H2_ + (kg - 512);
            const float4 av = *(const float4*)ap;
            As[lk + 0][lrow + hh * 64] = av.x;
            As[lk + 1][lrow + hh * 64] = av.y;
            As[lk + 2][lrow + hh * 64] = av.z;
            As[lk + 3][lrow + hh * 64] = av.w;
            const int n = n0 + lrow + hh * 64;
            const float4 bv = *(const float4*)(Wc + (size_t)n * K1_ + kg);
            Bs[lk + 0][lrow + hh * 64] = bv.x;
            Bs[lk + 1][lrow + hh * 64] = bv.y;
            Bs[lk + 2][lrow + hh * 64] = bv.z;
            Bs[lk + 3][lrow + hh * 64] = bv.w;
        }
        __syncthreads();
        #pragma unroll
        for (int kk = 0; kk < 16; ++kk) {
            float a[8], b[8];
            *(float4*)&a[0] = *(const float4*)&As[kk][ty * 8];
            *(float4*)&a[4] = *(const float4*)&As[kk][ty * 8 + 4];
            *(float4*)&b[0] = *(const float4*)&Bs[kk][tx * 8];
            *(float4*)&b[4] = *(const float4*)&Bs[kk][tx * 8 + 4];
            #pragma unroll
            for (int i = 0; i < 8; ++i)
                #pragma unroll
                for (int j = 0; j < 8; ++j)
                    acc[i][j] = fmaf(a[i], b[j], acc[i][j]);
        }
        __syncthreads();
    }
    float bb[8];
    #pragma unroll
    for (int j = 0; j < 8; ++j) bb[j] = biasc[n0 + tx * 8 + j];
    #pragma unroll
    for (int i = 0; i < 8; ++i) {
        const int m = m0 + ty * 8 + i;
        float* dst = Xih + (size_t)m * H_ + n0 + tx * 8;
        #pragma unroll
        for (int j = 0; j < 8; j += 4) {
            float4 o = make_float4(acc[i][j] + bb[j], acc[i][j + 1] + bb[j + 1],
                                   acc[i][j + 2] + bb[j + 2], acc[i][j + 3] + bb[j + 3]);
            *(float4*)(dst + j) = o;
        }
    }
}

// ---------------------------------------------------------------------------
// K6: RNN v2. One block of 1024 threads per user (16 waves for latency hiding).
// Thread (kslice, n4): kslice = tid>>7 owns k in [kslice*64, kslice*64+64);
// n4 = (tid&127)*4 owns outputs n4..n4+3 (float4 coalesced weight loads).
// First R_REG k-rows of each slice live in registers (loaded once, ~320 KB/CU);
// the rest stream from L2 each step. 8-way k-slice reduce via padded LDS.
// ---------------------------------------------------------------------------
constexpr int R_REG = 20;

__global__ __launch_bounds__(1024, 4) void k_rnn2(
    const float* __restrict__ Xih, const float* __restrict__ WhhT,
    const float* __restrict__ h0, float* __restrict__ rnn_t,
    float* __restrict__ hfin)
{
    const int u   = blockIdx.x;
    const int tid = threadIdx.x;
    const int kslice = tid >> 7;          // 0..7
    const int k0     = kslice * 64;
    const int n4     = (tid & 127) * 4;

    __shared__ float hs[H_];
    __shared__ float red[8][520];         // +8 pad breaks stride-512 bank pattern

    const float* wbase = WhhT + (size_t)k0 * H_ + n4;

    float4 wreg[R_REG];
    #pragma unroll
    for (int r = 0; r < R_REG; ++r)
        wreg[r] = *(const float4*)(wbase + (size_t)r * H_);

    if (tid < H_) hs[tid] = h0[(size_t)u * H_ + tid];
    __syncthreads();

    for (int s = 0; s < S_; ++s) {
        float4 acc = make_float4(0.f, 0.f, 0.f, 0.f);
        // streamed k-rows (independent loads; compiler pipelines them)
        #pragma unroll
        for (int j = R_REG; j < 64; ++j) {
            const float4 wv = *(const float4*)(wbase + (size_t)j * H_);
            const float hk = hs[k0 + j];
            acc.x = fmaf(wv.x, hk, acc.x);
            acc.y = fmaf(wv.y, hk, acc.y);
            acc.z = fmaf(wv.z, hk, acc.z);
            acc.w = fmaf(wv.w, hk, acc.w);
        }
        // register-resident k-rows
        #pragma unroll
        for (int r = 0; r < R_REG; ++r) {
            const float hk = hs[k0 + r];
            acc.x = fmaf(wreg[r].x, hk, acc.x);
            acc.y = fmaf(wreg[r].y, hk, acc.y);
            acc.z = fmaf(wreg[r].z, hk, acc.z);
            acc.w = fmaf(wreg[r].w, hk, acc.w);
        }
        *(float4*)&red[kslice][n4] = acc;
        __syncthreads();
        if (tid < H_) {
            float sum = red[0][tid];
            #pragma unroll
            for (int k = 1; k < 8; ++k) sum += red[k][tid];
            const float xv = Xih[((size_t)(s * U_ + u)) * H_ + tid];
            const float hn = tanhf(xv + sum);
            hs[tid] = hn;   // safe: all reads of hs finished before prior sync
            rnn_t[((size_t)u * S_ + s) * H_ + tid] = hn;
        }
        __syncthreads();
    }
    if (tid < H_) hfin[(size_t)u * H_ + tid] = hs[tid];
}

// ---------------------------------------------------------------------------
// K7: normalized attention weights.
// ---------------------------------------------------------------------------
__global__ void k_attw(const float* __restrict__ tt,
                       const float* __restrict__ ss,
                       float* __restrict__ Wn)
{
    const int b = blockIdx.x;          // u*256 + i
    const int u = b >> 8, i = b & 255;
    const int j = threadIdx.x;         // 256 = S
    const float ti  = tt[i * U_ + u];
    const float si0 = ss[(size_t)(i * U_ + u) * 2 + 0];
    const float si1 = ss[(size_t)(i * U_ + u) * 2 + 1];
    float w = 0.f;
    if (j <= i) {
        const float dt = ti - tt[j * U_ + u];
        const float arg = ((dt * 2.0f) * PI_F) / 86400.0f;
        const float ft = (cosf(arg) + 1.f) * 0.5f * expf(-(dt / 86400.0f) * 0.1f);
        const float dx = si0 - ss[(size_t)(j * U_ + u) * 2 + 0];
        const float dy = si1 - ss[(size_t)(j * U_ + u) * 2 + 1];
        const float ds = sqrtf(dx * dx + dy * dy);
        w = fmaf(ft, expf(-ds * 100.0f), 1e-10f);
    }
    __shared__ float red[256];
    red[j] = w;
    __syncthreads();
    for (int st = 128; st > 0; st >>= 1) {
        if (j < st) red[j] += red[j + st];
        __syncthreads();
    }
    const float den = red[0];
    Wn[((size_t)u * S_ + i) * S_ + j] = w / den;
}

// ---------------------------------------------------------------------------
// K8: per-user GEMM  outw[u][i][h] = sum_j Wn[u][i][j] * rnn_t[u][j][h]
// ---------------------------------------------------------------------------
__global__ __launch_bounds__(256) void k_att_gemm(
    const float* __restrict__ Wn, const float* __restrict__ rnn_t,
    float* __restrict__ outw)
{
    __shared__ float As[16][132];
    __shared__ float Bs[16][132];
    const int t = threadIdx.x;
    const int n0 = blockIdx.x * 128;
    const int m0 = blockIdx.y * 128;
    const int u  = blockIdx.z;
    const int lrow = t >> 2;
    const int lk = (t & 3) << 2;
    const int tx = t & 15, ty = t >> 4;
    const float* A = Wn + (size_t)u * S_ * S_;
    const float* B = rnn_t + (size_t)u * S_ * H_;
    float acc[8][8] = {};
    for (int k0 = 0; k0 < S_; k0 += 16) {
        #pragma unroll
        for (int hh = 0; hh < 2; ++hh) {
            const int m = m0 + lrow + hh * 64;
            const float4 av = *(const float4*)(A + (size_t)m * S_ + k0 + lk);
            As[lk + 0][lrow + hh * 64] = av.x;
            As[lk + 1][lrow + hh * 64] = av.y;
            As[lk + 2][lrow + hh * 64] = av.z;
            As[lk + 3][lrow + hh * 64] = av.w;
        }
        {   // B is k-major: Bs[kk][n] = B[k0+kk][n0+n]
            const int kk = t >> 4;           // 0..15
            const int nn = (t & 15) * 8;     // 0..120
            const float* bp = B + (size_t)(k0 + kk) * H_ + n0 + nn;
            *(float4*)&Bs[kk][nn]     = *(const float4*)bp;
            *(float4*)&Bs[kk][nn + 4] = *(const float4*)(bp + 4);
        }
        __syncthreads();
        #pragma unroll
        for (int kk = 0; kk < 16; ++kk) {
            float a[8], b[8];
            *(float4*)&a[0] = *(const float4*)&As[kk][ty * 8];
            *(float4*)&a[4] = *(const float4*)&As[kk][ty * 8 + 4];
            *(float4*)&b[0] = *(const float4*)&Bs[kk][tx * 8];
            *(float4*)&b[4] = *(const float4*)&Bs[kk][tx * 8 + 4];
            #pragma unroll
            for (int i = 0; i < 8; ++i)
                #pragma unroll
                for (int j = 0; j < 8; ++j)
                    acc[i][j] = fmaf(a[i], b[j], acc[i][j]);
        }
        __syncthreads();
    }
    #pragma unroll
    for (int i = 0; i < 8; ++i) {
        const int m = m0 + ty * 8 + i;
        float* dst = outw + ((size_t)u * S_ + m) * H_ + n0 + tx * 8;
        #pragma unroll
        for (int j = 0; j < 8; j += 4)
            *(float4*)(dst + j) = make_float4(acc[i][j], acc[i][j + 1],
                                              acc[i][j + 2], acc[i][j + 3]);
    }
}

// ---------------------------------------------------------------------------
// K9: final GEMM  y[m][v] = sum_k A2[m][k]*fc_w[v][k] + fc_b[v]
// ---------------------------------------------------------------------------
__global__ __launch_bounds__(256) void k_final_gemm(
    const int* __restrict__ au, const int* __restrict__ yslot,
    const float* __restrict__ outw, const float* __restrict__ user_w,
    const float* __restrict__ tab, const float* __restrict__ fc_w,
    const float* __restrict__ fc_b, float* __restrict__ y)
{
    __shared__ float As[16][132];
    __shared__ float Bs[16][132];
    const int t = threadIdx.x;
    const int n0 = blockIdx.x * 128;
    const int m0 = blockIdx.y * 128;
    const int lrow = t >> 2;
    const int lk = (t & 3) << 2;
    const int tx = t & 15, ty = t >> 4;
    float acc[8][8] = {};
    for (int k0 = 0; k0 < K2_; k0 += 16) {
        const int kg = k0 + lk;
        #pragma unroll
        for (int hh = 0; hh < 2; ++hh) {
            const int m = m0 + lrow + hh * 64;
            const int uu = m & 63, sb = m >> 6;
            const float* ap;
            if (kg < 512)       ap = outw + ((size_t)uu * S_ + sb) * H_ + kg;
            else if (kg < 1024) ap = user_w + (size_t)au[uu] * H_ + (kg - 512);
            else                ap = tab + (size_t)yslot[m] * H2_ + (kg - 1024);
            const float4 av = *(const float4*)ap;
            As[lk + 0][lrow + hh * 64] = av.x;
            As[lk + 1][lrow + hh * 64] = av.y;
            As[lk + 2][lrow + hh * 64] = av.z;
            As[lk + 3][lrow + hh * 64] = av.w;
            const int v = n0 + lrow + hh * 64;
            float4 bv = make_float4(0.f, 0.f, 0.f, 0.f);
            if (v < V_) bv = *(const float4*)(fc_w + (size_t)v * K2_ + kg);
            Bs[lk + 0][lrow + hh * 64] = bv.x;
            Bs[lk + 1][lrow + hh * 64] = bv.y;
            Bs[lk + 2][lrow + hh * 64] = bv.z;
            Bs[lk + 3][lrow + hh * 64] = bv.w;
        }
        __syncthreads();
        #pragma unroll
        for (int kk = 0; kk < 16; ++kk) {
            float a[8], b[8];
            *(float4*)&a[0] = *(const float4*)&As[kk][ty * 8];
            *(float4*)&a[4] = *(const float4*)&As[kk][ty * 8 + 4];
            *(float4*)&b[0] = *(const float4*)&Bs[kk][tx * 8];
            *(float4*)&b[4] = *(const float4*)&Bs[kk][tx * 8 + 4];
            #pragma unroll
            for (int i = 0; i < 8; ++i)
                #pragma unroll
                for (int j = 0; j < 8; ++j)
                    acc[i][j] = fmaf(a[i], b[j], acc[i][j]);
        }
        __syncthreads();
    }
    float bb[8];
    #pragma unroll
    for (int j = 0; j < 8; ++j) {
        const int col = n0 + tx * 8 + j;
        bb[j] = (col < V_) ? fc_b[col] : 0.f;
    }
    #pragma unroll
    for (int i = 0; i < 8; ++i) {
        const int m = m0 + ty * 8 + i;
        float* dst = y + (size_t)m * V_;
        #pragma unroll
        for (int j = 0; j < 8; j += 4) {
            const int col = n0 + tx * 8 + j;
            if (col < V_) {
                *(float4*)(dst + col) = make_float4(acc[i][j] + bb[j],
                                                    acc[i][j + 1] + bb[j + 1],
                                                    acc[i][j + 2] + bb[j + 2],
                                                    acc[i][j + 3] + bb[j + 3]);
            }
        }
    }
}

// ---------------------------------------------------------------------------
// Launch
// ---------------------------------------------------------------------------
extern "C" void kernel_launch(void* const* d_in, const int* in_sizes, int n_in,
                              void* d_out, int out_size, void* d_ws, size_t ws_size,
                              hipStream_t stream)
{
    const int*   x      = (const int*)  d_in[0];
    const float* tt     = (const float*)d_in[1];
    const int*   tslot  = (const int*)  d_in[2];
    const float* ss     = (const float*)d_in[3];
    const int*   yslot  = (const int*)  d_in[5];
    const float* h0     = (const float*)d_in[7];
    const int*   au     = (const int*)  d_in[8];
    const int*   wm     = (const int*)  d_in[9];
    const float* wwi    = (const float*)d_in[10];
    const float* sigma  = (const float*)d_in[11];
    const float* enc_w  = (const float*)d_in[12];
    const float* user_w = (const float*)d_in[13];
    const float* wenc   = (const float*)d_in[14];
    const float* fcpt_w = (const float*)d_in[15];
    const float* fcpt_b = (const float*)d_in[16];
    const float* W_ih   = (const float*)d_in[17];
    const float* W_hh   = (const float*)d_in[18];
    const float* b_ih   = (const float*)d_in[19];
    const float* b_hh   = (const float*)d_in[20];
    const float* fc_w   = (const float*)d_in[21];
    const float* fc_b   = (const float*)d_in[22];

    float* ws   = (float*)d_ws;
    float* ww    = ws + WW_OFF;
    float* tab   = ws + TAB_OFF;
    float* Wc    = ws + WC_OFF;
    float* biasc = ws + BIASC_OFF;
    float* WhhT  = ws + WHHT_OFF;
    float* Xih   = ws + XIH_OFF;
    float* rnn   = ws + RNN_OFF;
    float* Wn    = ws + WN_OFF;
    float* outw  = ws + OUTW_OFF;          // reuses Xih region (dead after RNN)

    float* y    = (float*)d_out;                          // [16384][5000]
    float* hfin = (float*)d_out + (size_t)S_ * U_ * V_;   // [64][512]

    k_week <<<168, 256, 0, stream>>>(sigma, wwi, ww);
    k_table<<<168, 256, 0, stream>>>(ww, wm, wenc, tab);
    k_wc   <<<dim3(3, 32), 256, 0, stream>>>(W_ih, fcpt_w, Wc);
    k_biasc<<<2, 256, 0, stream>>>(W_ih, fcpt_b, b_ih, b_hh, biasc);
    k_whhT <<<dim3(16, 16), dim3(32, 8), 0, stream>>>(W_hh, WhhT);
    k_xih_gemm<<<dim3(4, 128), 256, 0, stream>>>(x, tslot, enc_w, tab, Wc, biasc, Xih);
    k_rnn2 <<<64, 1024, 0, stream>>>(Xih, WhhT, h0, rnn, hfin);
    k_attw <<<16384, 256, 0, stream>>>(tt, ss, Wn);
    k_att_gemm<<<dim3(4, 2, 64), 256, 0, stream>>>(Wn, rnn, outw);
    k_final_gemm<<<dim3(40, 128), 256, 0, stream>>>(au, yslot, outw, user_w, tab,
                                                    fc_w, fc_b, y);
}

// Round 3
// 5677.047 us; speedup vs baseline: 1.4974x; 1.4974x over previous
//
#include <hip/hip_runtime.h>

// ---------------------------------------------------------------------------
// Sizes (fixed by the problem)
// ---------------------------------------------------------------------------
constexpr int S_ = 256, U_ = 64, H_ = 512, H2_ = 256, V_ = 5000;
constexpr int K1_ = H_ + H2_;       // 768  (x_emb | t_emb1)
constexpr int K2_ = 2 * H_ + H2_;   // 1280 (out_w | p_u | t_emb2)

#define PI_F 3.14159265358979323846f

// ---------------------------------------------------------------------------
// Workspace layout (float offsets). Total = 21,699,072 floats = 86.8 MB.
// ---------------------------------------------------------------------------
constexpr size_t WW_OFF    = 0;          // 168*168  = 28224 (padded to 28672)
constexpr size_t TAB_OFF   = 28672;      // 168*256  = 43008
constexpr size_t WC_OFF    = 71680;      // 512*768  = 393216  (W_ih @ fcpt_w)
constexpr size_t BIASC_OFF = 464896;     // 512
constexpr size_t WHHT_OFF  = 465408;     // 512*512  = 262144  (W_hh transposed)
constexpr size_t XIH_OFF   = 727552;     // 16384*512 = 8388608 (reused as OUTW)
constexpr size_t RNN_OFF   = 9116160;    // 64*256*512 = 8388608 ([u][s][h])
constexpr size_t WN_OFF    = 17504768;   // 64*256*256 = 4194304 (normalized attn W)
constexpr size_t OUTW_OFF  = XIH_OFF;    // Xih dead after RNN -> reuse

// ---------------------------------------------------------------------------
// K1: week_weight[i][j] = gauss(sigma_i, wwi[i][j]) row-normalized
// ---------------------------------------------------------------------------
__global__ void k_week(const float* __restrict__ sigma,
                       const float* __restrict__ wwi,
                       float* __restrict__ ww)
{
    const int i = blockIdx.x;
    const int j = threadIdx.x;                 // 256 threads, 168 active
    const float sig  = fabsf(sigma[i]);
    const float sig2 = sig * sig;
    float v = 0.f;
    if (j < 168) {
        const float xv = wwi[i * 168 + j];
        v = (1.f / sqrtf(2.f * PI_F * sig2)) * expf(-(xv * xv) / (2.f * sig2));
    }
    __shared__ float red[256];
    red[j] = v;
    __syncthreads();
    for (int st = 128; st > 0; st >>= 1) {
        if (j < st) red[j] += red[j + st];
        __syncthreads();
    }
    const float den = red[0];
    if (j < 168) ww[i * 168 + j] = v / den;
}

// ---------------------------------------------------------------------------
// K2: tab[slot][h] = sum_k ww[slot][k] * wenc[wm[slot][k]][h]   (h < 256)
// ---------------------------------------------------------------------------
__global__ void k_table(const float* __restrict__ ww,
                        const int* __restrict__ wm,
                        const float* __restrict__ wenc,
                        float* __restrict__ tab)
{
    const int slot = blockIdx.x;
    const int t = threadIdx.x;                 // 256 = H2
    __shared__ float wws[168];
    __shared__ int   wms[168];
    if (t < 168) {
        wws[t] = ww[slot * 168 + t];
        wms[t] = wm[slot * 168 + t];
    }
    __syncthreads();
    float acc = 0.f;
    #pragma unroll 4
    for (int k = 0; k < 168; ++k)
        acc = fmaf(wws[k], wenc[(size_t)wms[k] * H2_ + t], acc);
    tab[(size_t)slot * H2_ + t] = acc;
}

// ---------------------------------------------------------------------------
// K3: Wc[n][k] = sum_m W_ih[n][m] * fcpt_w[m][k]   (512 x 768, K=512)
// ---------------------------------------------------------------------------
__global__ void k_wc(const float* __restrict__ W_ih,
                     const float* __restrict__ fcpt_w,
                     float* __restrict__ Wc)
{
    const int kk = blockIdx.x * 256 + threadIdx.x;   // 0..767
    const int n0 = blockIdx.y * 16;
    float acc[16] = {};
    for (int m = 0; m < H_; ++m) {
        const float fw = fcpt_w[(size_t)m * K1_ + kk];
        #pragma unroll
        for (int j = 0; j < 16; ++j)
            acc[j] = fmaf(W_ih[(size_t)(n0 + j) * H_ + m], fw, acc[j]);
    }
    #pragma unroll
    for (int j = 0; j < 16; ++j)
        Wc[(size_t)(n0 + j) * K1_ + kk] = acc[j];
}

// K3b: biasc[n] = b_ih[n] + b_hh[n] + sum_k W_ih[n][k] * fcpt_b[k]
__global__ void k_biasc(const float* __restrict__ W_ih,
                        const float* __restrict__ fcpt_b,
                        const float* __restrict__ b_ih,
                        const float* __restrict__ b_hh,
                        float* __restrict__ biasc)
{
    const int n = blockIdx.x * 256 + threadIdx.x;
    float acc = b_ih[n] + b_hh[n];
    for (int k = 0; k < H_; ++k)
        acc = fmaf(W_ih[(size_t)n * H_ + k], fcpt_b[k], acc);
    biasc[n] = acc;
}

// ---------------------------------------------------------------------------
// K4: WhhT[k][o] = W_hh[o][k]  (512x512 transpose, 32x32 LDS tiles)
// ---------------------------------------------------------------------------
__global__ void k_whhT(const float* __restrict__ Whh, float* __restrict__ WhhT)
{
    __shared__ float tile[32][33];
    const int bx = blockIdx.x, by = blockIdx.y;
    const int tx = threadIdx.x;                // 0..31
    for (int r = threadIdx.y; r < 32; r += 8)
        tile[r][tx] = Whh[(size_t)(by * 32 + r) * H_ + bx * 32 + tx];
    __syncthreads();
    for (int r = threadIdx.y; r < 32; r += 8)
        WhhT[(size_t)(bx * 32 + r) * H_ + by * 32 + tx] = tile[tx][r];
}

// ---------------------------------------------------------------------------
// K5: gathered GEMM  Xih[m][n] = sum_k A1[m][k] * Wc[n][k] + biasc[n]
// ---------------------------------------------------------------------------
__global__ __launch_bounds__(256) void k_xih_gemm(
    const int* __restrict__ x, const int* __restrict__ tslot,
    const float* __restrict__ enc_w, const float* __restrict__ tab,
    const float* __restrict__ Wc, const float* __restrict__ biasc,
    float* __restrict__ Xih)
{
    __shared__ float As[16][132];
    __shared__ float Bs[16][132];
    const int t = threadIdx.x;
    const int n0 = blockIdx.x * 128;
    const int m0 = blockIdx.y * 128;
    const int lrow = t >> 2;
    const int lk = (t & 3) << 2;
    const int tx = t & 15, ty = t >> 4;
    float acc[8][8] = {};
    for (int k0 = 0; k0 < K1_; k0 += 16) {
        const int kg = k0 + lk;
        #pragma unroll
        for (int hh = 0; hh < 2; ++hh) {
            const int m = m0 + lrow + hh * 64;
            const float* ap;
            if (kg < 512) ap = enc_w + (size_t)x[m] * H_ + kg;
            else          ap = tab + (size_t)tslot[m] * H2_ + (kg - 512);
            const float4 av = *(const float4*)ap;
            As[lk + 0][lrow + hh * 64] = av.x;
            As[lk + 1][lrow + hh * 64] = av.y;
            As[lk + 2][lrow + hh * 64] = av.z;
            As[lk + 3][lrow + hh * 64] = av.w;
            const int n = n0 + lrow + hh * 64;
            const float4 bv = *(const float4*)(Wc + (size_t)n * K1_ + kg);
            Bs[lk + 0][lrow + hh * 64] = bv.x;
            Bs[lk + 1][lrow + hh * 64] = bv.y;
            Bs[lk + 2][lrow + hh * 64] = bv.z;
            Bs[lk + 3][lrow + hh * 64] = bv.w;
        }
        __syncthreads();
        #pragma unroll
        for (int kk = 0; kk < 16; ++kk) {
            float a[8], b[8];
            *(float4*)&a[0] = *(const float4*)&As[kk][ty * 8];
            *(float4*)&a[4] = *(const float4*)&As[kk][ty * 8 + 4];
            *(float4*)&b[0] = *(const float4*)&Bs[kk][tx * 8];
            *(float4*)&b[4] = *(const float4*)&Bs[kk][tx * 8 + 4];
            #pragma unroll
            for (int i = 0; i < 8; ++i)
                #pragma unroll
                for (int j = 0; j < 8; ++j)
                    acc[i][j] = fmaf(a[i], b[j], acc[i][j]);
        }
        __syncthreads();
    }
    float bb[8];
    #pragma unroll
    for (int j = 0; j < 8; ++j) bb[j] = biasc[n0 + tx * 8 + j];
    #pragma unroll
    for (int i = 0; i < 8; ++i) {
        const int m = m0 + ty * 8 + i;
        float* dst = Xih + (size_t)m * H_ + n0 + tx * 8;
        #pragma unroll
        for (int j = 0; j < 8; j += 4) {
            float4 o = make_float4(acc[i][j] + bb[j], acc[i][j + 1] + bb[j + 1],
                                   acc[i][j + 2] + bb[j + 2], acc[i][j + 3] + bb[j + 3]);
            *(float4*)(dst + j) = o;
        }
    }
}

// ---------------------------------------------------------------------------
// K6: RNN v3 — pure L2 streamer, no register-resident W (v2's wreg spilled to
// scratch: FETCH 5.15 GB == 64*1024*320B*256 exactly). 1024 thr = 16 waves;
// thread (kslice=tid>>7, n4=(tid&127)*4) streams 64 float4 W rows per step.
// W (1 MB) is L2-resident per XCD; 8 blocks/XCD -> ~1.9 us/step L2-BW bound.
// #pragma unroll 16 bounds in-flight regs (~64 VGPR) below the spill cliff.
// ---------------------------------------------------------------------------
__global__ __launch_bounds__(1024) void k_rnn3(
    const float* __restrict__ Xih, const float* __restrict__ WhhT,
    const float* __restrict__ h0, float* __restrict__ rnn_t,
    float* __restrict__ hfin)
{
    const int u   = blockIdx.x;
    const int tid = threadIdx.x;
    const int kslice = tid >> 7;          // 0..7
    const int k0     = kslice * 64;
    const int n4     = (tid & 127) * 4;

    __shared__ float hs[H_];
    __shared__ float red[8][520];         // +8 pad breaks stride-512 bank pattern

    const float* wbase = WhhT + (size_t)k0 * H_ + n4;

    if (tid < H_) hs[tid] = h0[(size_t)u * H_ + tid];
    __syncthreads();

    for (int s = 0; s < S_; ++s) {
        float4 acc = make_float4(0.f, 0.f, 0.f, 0.f);
        #pragma unroll 16
        for (int j = 0; j < 64; ++j) {
            const float4 wv = *(const float4*)(wbase + (size_t)j * H_);
            const float hk = hs[k0 + j];
            acc.x = fmaf(wv.x, hk, acc.x);
            acc.y = fmaf(wv.y, hk, acc.y);
            acc.z = fmaf(wv.z, hk, acc.z);
            acc.w = fmaf(wv.w, hk, acc.w);
        }
        *(float4*)&red[kslice][n4] = acc;
        __syncthreads();
        if (tid < H_) {
            float sum = red[0][tid];
            #pragma unroll
            for (int k = 1; k < 8; ++k) sum += red[k][tid];
            const float xv = Xih[((size_t)(s * U_ + u)) * H_ + tid];
            const float hn = tanhf(xv + sum);
            hs[tid] = hn;   // safe: all hs reads completed before this barrier
            rnn_t[((size_t)u * S_ + s) * H_ + tid] = hn;
        }
        __syncthreads();
    }
    if (tid < H_) hfin[(size_t)u * H_ + tid] = hs[tid];
}

// ---------------------------------------------------------------------------
// K7: normalized attention weights.
// ---------------------------------------------------------------------------
__global__ void k_attw(const float* __restrict__ tt,
                       const float* __restrict__ ss,
                       float* __restrict__ Wn)
{
    const int b = blockIdx.x;          // u*256 + i
    const int u = b >> 8, i = b & 255;
    const int j = threadIdx.x;         // 256 = S
    const float ti  = tt[i * U_ + u];
    const float si0 = ss[(size_t)(i * U_ + u) * 2 + 0];
    const float si1 = ss[(size_t)(i * U_ + u) * 2 + 1];
    float w = 0.f;
    if (j <= i) {
        const float dt = ti - tt[j * U_ + u];
        const float arg = ((dt * 2.0f) * PI_F) / 86400.0f;
        const float ft = (cosf(arg) + 1.f) * 0.5f * expf(-(dt / 86400.0f) * 0.1f);
        const float dx = si0 - ss[(size_t)(j * U_ + u) * 2 + 0];
        const float dy = si1 - ss[(size_t)(j * U_ + u) * 2 + 1];
        const float ds = sqrtf(dx * dx + dy * dy);
        w = fmaf(ft, expf(-ds * 100.0f), 1e-10f);
    }
    __shared__ float red[256];
    red[j] = w;
    __syncthreads();
    for (int st = 128; st > 0; st >>= 1) {
        if (j < st) red[j] += red[j + st];
        __syncthreads();
    }
    const float den = red[0];
    Wn[((size_t)u * S_ + i) * S_ + j] = w / den;
}

// ---------------------------------------------------------------------------
// K8: per-user GEMM  outw[u][i][h] = sum_j Wn[u][i][j] * rnn_t[u][j][h]
// ---------------------------------------------------------------------------
__global__ __launch_bounds__(256) void k_att_gemm(
    const float* __restrict__ Wn, const float* __restrict__ rnn_t,
    float* __restrict__ outw)
{
    __shared__ float As[16][132];
    __shared__ float Bs[16][132];
    const int t = threadIdx.x;
    const int n0 = blockIdx.x * 128;
    const int m0 = blockIdx.y * 128;
    const int u  = blockIdx.z;
    const int lrow = t >> 2;
    const int lk = (t & 3) << 2;
    const int tx = t & 15, ty = t >> 4;
    const float* A = Wn + (size_t)u * S_ * S_;
    const float* B = rnn_t + (size_t)u * S_ * H_;
    float acc[8][8] = {};
    for (int k0 = 0; k0 < S_; k0 += 16) {
        #pragma unroll
        for (int hh = 0; hh < 2; ++hh) {
            const int m = m0 + lrow + hh * 64;
            const float4 av = *(const float4*)(A + (size_t)m * S_ + k0 + lk);
            As[lk + 0][lrow + hh * 64] = av.x;
            As[lk + 1][lrow + hh * 64] = av.y;
            As[lk + 2][lrow + hh * 64] = av.z;
            As[lk + 3][lrow + hh * 64] = av.w;
        }
        {   // B is k-major: Bs[kk][n] = B[k0+kk][n0+n]
            const int kk = t >> 4;           // 0..15
            const int nn = (t & 15) * 8;     // 0..120
            const float* bp = B + (size_t)(k0 + kk) * H_ + n0 + nn;
            *(float4*)&Bs[kk][nn]     = *(const float4*)bp;
            *(float4*)&Bs[kk][nn + 4] = *(const float4*)(bp + 4);
        }
        __syncthreads();
        #pragma unroll
        for (int kk = 0; kk < 16; ++kk) {
            float a[8], b[8];
            *(float4*)&a[0] = *(const float4*)&As[kk][ty * 8];
            *(float4*)&a[4] = *(const float4*)&As[kk][ty * 8 + 4];
            *(float4*)&b[0] = *(const float4*)&Bs[kk][tx * 8];
            *(float4*)&b[4] = *(const float4*)&Bs[kk][tx * 8 + 4];
            #pragma unroll
            for (int i = 0; i < 8; ++i)
                #pragma unroll
                for (int j = 0; j < 8; ++j)
                    acc[i][j] = fmaf(a[i], b[j], acc[i][j]);
        }
        __syncthreads();
    }
    #pragma unroll
    for (int i = 0; i < 8; ++i) {
        const int m = m0 + ty * 8 + i;
        float* dst = outw + ((size_t)u * S_ + m) * H_ + n0 + tx * 8;
        #pragma unroll
        for (int j = 0; j < 8; j += 4)
            *(float4*)(dst + j) = make_float4(acc[i][j], acc[i][j + 1],
                                              acc[i][j + 2], acc[i][j + 3]);
    }
}

// ---------------------------------------------------------------------------
// K9: final GEMM  y[m][v] = sum_k A2[m][k]*fc_w[v][k] + fc_b[v]
// ---------------------------------------------------------------------------
__global__ __launch_bounds__(256) void k_final_gemm(
    const int* __restrict__ au, const int* __restrict__ yslot,
    const float* __restrict__ outw, const float* __restrict__ user_w,
    const float* __restrict__ tab, const float* __restrict__ fc_w,
    const float* __restrict__ fc_b, float* __restrict__ y)
{
    __shared__ float As[16][132];
    __shared__ float Bs[16][132];
    const int t = threadIdx.x;
    const int n0 = blockIdx.x * 128;
    const int m0 = blockIdx.y * 128;
    const int lrow = t >> 2;
    const int lk = (t & 3) << 2;
    const int tx = t & 15, ty = t >> 4;
    float acc[8][8] = {};
    for (int k0 = 0; k0 < K2_; k0 += 16) {
        const int kg = k0 + lk;
        #pragma unroll
        for (int hh = 0; hh < 2; ++hh) {
            const int m = m0 + lrow + hh * 64;
            const int uu = m & 63, sb = m >> 6;
            const float* ap;
            if (kg < 512)       ap = outw + ((size_t)uu * S_ + sb) * H_ + kg;
            else if (kg < 1024) ap = user_w + (size_t)au[uu] * H_ + (kg - 512);
            else                ap = tab + (size_t)yslot[m] * H2_ + (kg - 1024);
            const float4 av = *(const float4*)ap;
            As[lk + 0][lrow + hh * 64] = av.x;
            As[lk + 1][lrow + hh * 64] = av.y;
            As[lk + 2][lrow + hh * 64] = av.z;
            As[lk + 3][lrow + hh * 64] = av.w;
            const int v = n0 + lrow + hh * 64;
            float4 bv = make_float4(0.f, 0.f, 0.f, 0.f);
            if (v < V_) bv = *(const float4*)(fc_w + (size_t)v * K2_ + kg);
            Bs[lk + 0][lrow + hh * 64] = bv.x;
            Bs[lk + 1][lrow + hh * 64] = bv.y;
            Bs[lk + 2][lrow + hh * 64] = bv.z;
            Bs[lk + 3][lrow + hh * 64] = bv.w;
        }
        __syncthreads();
        #pragma unroll
        for (int kk = 0; kk < 16; ++kk) {
            float a[8], b[8];
            *(float4*)&a[0] = *(const float4*)&As[kk][ty * 8];
            *(float4*)&a[4] = *(const float4*)&As[kk][ty * 8 + 4];
            *(float4*)&b[0] = *(const float4*)&Bs[kk][tx * 8];
            *(float4*)&b[4] = *(const float4*)&Bs[kk][tx * 8 + 4];
            #pragma unroll
            for (int i = 0; i < 8; ++i)
                #pragma unroll
                for (int j = 0; j < 8; ++j)
                    acc[i][j] = fmaf(a[i], b[j], acc[i][j]);
        }
        __syncthreads();
    }
    float bb[8];
    #pragma unroll
    for (int j = 0; j < 8; ++j) {
        const int col = n0 + tx * 8 + j;
        bb[j] = (col < V_) ? fc_b[col] : 0.f;
    }
    #pragma unroll
    for (int i = 0; i < 8; ++i) {
        const int m = m0 + ty * 8 + i;
        float* dst = y + (size_t)m * V_;
        #pragma unroll
        for (int j = 0; j < 8; j += 4) {
            const int col = n0 + tx * 8 + j;
            if (col < V_) {
                *(float4*)(dst + col) = make_float4(acc[i][j] + bb[j],
                                                    acc[i][j + 1] + bb[j + 1],
                                                    acc[i][j + 2] + bb[j + 2],
                                                    acc[i][j + 3] + bb[j + 3]);
            }
        }
    }
}

// ---------------------------------------------------------------------------
// Launch
// ---------------------------------------------------------------------------
extern "C" void kernel_launch(void* const* d_in, const int* in_sizes, int n_in,
                              void* d_out, int out_size, void* d_ws, size_t ws_size,
                              hipStream_t stream)
{
    const int*   x      = (const int*)  d_in[0];
    const float* tt     = (const float*)d_in[1];
    const int*   tslot  = (const int*)  d_in[2];
    const float* ss     = (const float*)d_in[3];
    const int*   yslot  = (const int*)  d_in[5];
    const float* h0     = (const float*)d_in[7];
    const int*   au     = (const int*)  d_in[8];
    const int*   wm     = (const int*)  d_in[9];
    const float* wwi    = (const float*)d_in[10];
    const float* sigma  = (const float*)d_in[11];
    const float* enc_w  = (const float*)d_in[12];
    const float* user_w = (const float*)d_in[13];
    const float* wenc   = (const float*)d_in[14];
    const float* fcpt_w = (const float*)d_in[15];
    const float* fcpt_b = (const float*)d_in[16];
    const float* W_ih   = (const float*)d_in[17];
    const float* W_hh   = (const float*)d_in[18];
    const float* b_ih   = (const float*)d_in[19];
    const float* b_hh   = (const float*)d_in[20];
    const float* fc_w   = (const float*)d_in[21];
    const float* fc_b   = (const float*)d_in[22];

    float* ws   = (float*)d_ws;
    float* ww    = ws + WW_OFF;
    float* tab   = ws + TAB_OFF;
    float* Wc    = ws + WC_OFF;
    float* biasc = ws + BIASC_OFF;
    float* WhhT  = ws + WHHT_OFF;
    float* Xih   = ws + XIH_OFF;
    float* rnn   = ws + RNN_OFF;
    float* Wn    = ws + WN_OFF;
    float* outw  = ws + OUTW_OFF;          // reuses Xih region (dead after RNN)

    float* y    = (float*)d_out;                          // [16384][5000]
    float* hfin = (float*)d_out + (size_t)S_ * U_ * V_;   // [64][512]

    k_week <<<168, 256, 0, stream>>>(sigma, wwi, ww);
    k_table<<<168, 256, 0, stream>>>(ww, wm, wenc, tab);
    k_wc   <<<dim3(3, 32), 256, 0, stream>>>(W_ih, fcpt_w, Wc);
    k_biasc<<<2, 256, 0, stream>>>(W_ih, fcpt_b, b_ih, b_hh, biasc);
    k_whhT <<<dim3(16, 16), dim3(32, 8), 0, stream>>>(W_hh, WhhT);
    k_xih_gemm<<<dim3(4, 128), 256, 0, stream>>>(x, tslot, enc_w, tab, Wc, biasc, Xih);
    k_rnn3 <<<64, 1024, 0, stream>>>(Xih, WhhT, h0, rnn, hfin);
    k_attw <<<16384, 256, 0, stream>>>(tt, ss, Wn);
    k_att_gemm<<<dim3(4, 2, 64), 256, 0, stream>>>(Wn, rnn, outw);
    k_final_gemm<<<dim3(40, 128), 256, 0, stream>>>(au, yslot, outw, user_w, tab,
                                                    fc_w, fc_b, y);
}